// Round 5
// baseline (411.766 us; speedup 1.0000x reference)
//
#include <hip/hip_runtime.h>

typedef __attribute__((ext_vector_type(8))) short short8;
typedef __attribute__((ext_vector_type(4))) float floatx4;

#define TT 8            // t-values per block
#define XS_PITCH 264    // per-c pitch (TT*32 + 8) shorts -> bank-break, 16B-aligned rows
#define KCP 200         // XAs row pitch shorts (192 + 8), 400B rows -> bank-friendly

// LDS overlay map (bytes):
//   [0      .. 33792) Xs   : bf16 x tile [c][t][vpad32]          (33792)
//   [33792  .. 46592) XA0  : bf16 [w][kc] double buffer 0        (12800)
//   [46592  .. 59392) XA1  : double buffer 1                     (12800)
//   [59392  .. 59776) colsumL[96]
//   [59776  .. 60032) sL[64]
//   [60032  .. 60288) b2L[64]
//   [60288  .. 61056) bcL[192]
//   post-loop: OutT f32 [co][t*25+w] packed (51200) overlays Xs+XA0+XA1
#define SMEM_BYTES 61056

__device__ __forceinline__ float bf2f(unsigned short u) {
    unsigned int xx = ((unsigned int)u) << 16;
    return __uint_as_float(xx);
}
__device__ __forceinline__ unsigned short f2bf(float f) {
    unsigned int xx = __float_as_uint(f);
    unsigned int r = (xx + 0x7fffu + ((xx >> 16) & 1u)) >> 16;
    return (unsigned short)r;
}

__global__ __launch_bounds__(512, 4) void gcn_fused(
    const float* __restrict__ x,  const float* __restrict__ A,
    const float* __restrict__ PA, const float* __restrict__ Wc,
    const float* __restrict__ bc, const float* __restrict__ gamma_,
    const float* __restrict__ beta_, const float* __restrict__ mean_,
    const float* __restrict__ var_, float* __restrict__ out)
{
#if defined(__gfx950__)
    __shared__ __align__(16) unsigned char smem[SMEM_BYTES];
    unsigned short* Xs  = (unsigned short*)smem;
    unsigned short* XA0 = (unsigned short*)(smem + 33792);
    unsigned short* XA1 = (unsigned short*)(smem + 46592);
    float* colsumL = (float*)(smem + 59392);
    float* sL      = (float*)(smem + 59776);
    float* b2L     = (float*)(smem + 60032);
    float* bcL     = (float*)(smem + 60288);
    float* OutT    = (float*)smem;           // post-loop overlay

    const int tid = threadIdx.x;
    const int n  = blockIdx.x >> 5;
    const int t0 = (blockIdx.x & 31) * TT;

    // ---------------- staging: x tile as float4 (16B-aligned segments) ----------------
    const float* xblk = x + (size_t)n * 409600 + t0 * 25;
    for (int idx = tid; idx < 3200; idx += 512) {      // 64 c * 50 float4
        int c = idx / 50, j4 = idx - c * 50;
        float4 val = *(const float4*)(xblk + c * 6400 + j4 * 4);
        int flat = j4 * 4;
#pragma unroll
        for (int e = 0; e < 4; ++e) {
            int f = flat + e;
            int t = f / 25, v = f - t * 25;
            Xs[c * XS_PITCH + t * 32 + v] = f2bf(((const float*)&val)[e]);
        }
    }
    // zero the v=25..31 pad (read by quad=3 fragments)
    for (int idx = tid; idx < 64 * TT * 7; idx += 512) {
        int c = idx / 56, r = idx - c * 56;
        int t = r / 7, v = 25 + (r - t * 7);
        Xs[c * XS_PITCH + t * 32 + v] = 0;
    }
    if (tid < 96) {
        int k = tid >> 5, w = tid & 31;
        float s = 0.f;
        if (w < 25)
            for (int v = 0; v < 25; ++v) {
                int ai = (k * 25 + v) * 25 + w;
                s += A[ai] * PA[ai];
            }
        colsumL[tid] = s;
    }
    if (tid < 64) {
        float sc = gamma_[tid] * rsqrtf(var_[tid] + 1e-5f);
        sL[tid]  = sc;
        b2L[tid] = beta_[tid] - mean_[tid] * sc;
    }
    if (tid < 192) bcL[tid] = bc[tid];

    const int wave = tid >> 6, lane = tid & 63;
    const int l15 = lane & 15, quad = lane >> 4;

    // stage A' fragments directly from global (A/PA are 7.5 KB, L2-hot)
    const int ntA = wave & 3, wmA = wave >> 2;
    union U8 { short8 v; unsigned short s[8]; };
    short8 aA[3];
#pragma unroll
    for (int ii = 0; ii < 3; ++ii) {
        int mt = wmA + 2 * ii;
        int kw = mt * 16 + l15;
        int k = kw >> 5, w = kw & 31;
        U8 u;
#pragma unroll
        for (int j = 0; j < 8; ++j) {
            int v2 = quad * 8 + j;
            float a = 0.f;
            if (w < 25 && v2 < 25) {
                int ai = (k * 25 + v2) * 25 + w;
                a = A[ai] * PA[ai];
            }
            u.s[j] = f2bf(a);
        }
        aA[ii] = u.v;
    }

    // stage B' W2 fragments: W2[co][k*64+c] = Wc[k*64+co][c]
    const int cot = wave & 3, wt = wave >> 2;
    short8 wf[6];
#pragma unroll
    for (int ks = 0; ks < 6; ++ks) {
        int k = ks >> 1;
        int co = cot * 16 + l15;
        int cpart = (ks & 1) * 32 + quad * 8;
        const float* wp = &Wc[(k * 64 + co) * 64 + cpart];
        U8 u;
#pragma unroll
        for (int j = 0; j < 8; ++j) u.s[j] = f2bf(wp[j]);
        wf[ks] = u.v;
    }

    __syncthreads();

    const int w = wt * 16 + l15;
    float vals[TT][4];

#pragma unroll
    for (int t = 0; t < TT; ++t) {
        unsigned short* XAw = (t & 1) ? XA1 : XA0;
        // ---- A': XA^T(kw,c) = Aeff^T(kw,v) @ X_t(v,c) ----
        short8 xb = *(const short8*)&Xs[(ntA * 16 + l15) * XS_PITCH + t * 32 + quad * 8];
        floatx4 fr[3];
#pragma unroll
        for (int ii = 0; ii < 3; ++ii) {
            floatx4 z0 = {0.f, 0.f, 0.f, 0.f};
            fr[ii] = __builtin_amdgcn_mfma_f32_16x16x32_bf16(aA[ii], xb, z0, 0, 0, 0);
        }
#pragma unroll
        for (int ii = 0; ii < 3; ++ii) {
            int mt = wmA + 2 * ii;
#pragma unroll
            for (int r = 0; r < 4; ++r) {
                int kw = mt * 16 + quad * 4 + r;
                int ww = kw & 31, k = kw >> 5;
                XAw[ww * KCP + k * 64 + ntA * 16 + l15] = f2bf(fr[ii][r]);
            }
        }
        __syncthreads();   // single barrier per t (XAs double-buffered)

        // ---- B': Z(co,w) = W2(co,kc) @ XA(kc,w) ----
        floatx4 zacc = {0.f, 0.f, 0.f, 0.f};
        const unsigned short* xr = &XAw[(wt * 16 + l15) * KCP];
#pragma unroll
        for (int ks = 0; ks < 6; ++ks) {
            short8 bfr = *(const short8*)&xr[ks * 32 + quad * 8];
            zacc = __builtin_amdgcn_mfma_f32_16x16x32_bf16(wf[ks], bfr, zacc, 0, 0, 0);
        }

        // ---- epilogue to registers (no global stores in loop) ----
        float cs0 = colsumL[w], cs1 = colsumL[32 + w], cs2 = colsumL[64 + w];
#pragma unroll
        for (int r = 0; r < 4; ++r) {
            int co = cot * 16 + quad * 4 + r;
            float bterm = bcL[co] * cs0 + bcL[64 + co] * cs1 + bcL[128 + co] * cs2;
            float xres = bf2f(Xs[co * XS_PITCH + t * 32 + w]);
            vals[t][r] = fmaxf(sL[co] * (zacc[r] + bterm) + b2L[co] + xres, 0.f);
        }
    }

    __syncthreads();   // Xs/XAs dead -> overlay OutT
    if (w < 25) {
#pragma unroll
        for (int t = 0; t < TT; ++t)
#pragma unroll
            for (int r = 0; r < 4; ++r) {
                int co = cot * 16 + quad * 4 + r;
                OutT[co * 200 + t * 25 + w] = vals[t][r];
            }
    }
    __syncthreads();

    // coalesced float4 stores of the packed tile
    float* oblk = out + (size_t)n * 409600 + t0 * 25;
    for (int idx = tid; idx < 3200; idx += 512) {
        int co = idx / 50, j4 = idx - co * 50;
        float4 vv = *(const float4*)&OutT[co * 200 + j4 * 4];
        *(float4*)(oblk + co * 6400 + j4 * 4) = vv;
    }
#else
    (void)x; (void)A; (void)PA; (void)Wc; (void)bc;
    (void)gamma_; (void)beta_; (void)mean_; (void)var_; (void)out;
#endif
}

extern "C" void kernel_launch(void* const* d_in, const int* in_sizes, int n_in,
                              void* d_out, int out_size, void* d_ws, size_t ws_size,
                              hipStream_t stream) {
    (void)in_sizes; (void)n_in; (void)d_ws; (void)ws_size; (void)out_size;
    gcn_fused<<<dim3(64 * 32), dim3(512), 0, stream>>>(
        (const float*)d_in[0],   // x
        (const float*)d_in[1],   // A
        (const float*)d_in[2],   // PA
        (const float*)d_in[3],   // Wc
        (const float*)d_in[4],   // bc
        (const float*)d_in[5],   // gamma
        (const float*)d_in[6],   // beta
        (const float*)d_in[7],   // mean
        (const float*)d_in[8],   // var
        (float*)d_out);
}

// Round 6
// 376.742 us; speedup vs baseline: 1.0930x; 1.0930x over previous
//
#include <hip/hip_runtime.h>

typedef __attribute__((ext_vector_type(8))) short short8;
typedef __attribute__((ext_vector_type(4))) float floatx4;

#define XSP 72     // Xs pitch (shorts): 2t*32v + 8 pad  -> 144B rows, 16B-aligned
#define ASP 32     // AsL pitch (shorts): 64B rows
#define KCP 200    // XA row pitch (shorts): 400B rows -> 2-way (free) bank pattern

__device__ __forceinline__ float bf2f(unsigned short u) {
    unsigned int xx = ((unsigned int)u) << 16;
    return __uint_as_float(xx);
}
__device__ __forceinline__ unsigned short f2bf(float f) {
    unsigned int xx = __float_as_uint(f);
    unsigned int r = (xx + 0x7fffu + ((xx >> 16) & 1u)) >> 16;
    return (unsigned short)r;
}

// LDS: Xs 9216 + AsL 6144 + XA 25600 + colsum 384 + sL 256 + b2L 256 + bcL 768
//    = 42624 B  -> 3 blocks/CU (LDS-wise), well under the 64 KiB workgroup cap.
__global__ __launch_bounds__(512) void gcn_fused(
    const float* __restrict__ x,  const float* __restrict__ A,
    const float* __restrict__ PA, const float* __restrict__ Wc,
    const float* __restrict__ bc, const float* __restrict__ gamma_,
    const float* __restrict__ beta_, const float* __restrict__ mean_,
    const float* __restrict__ var_, float* __restrict__ out)
{
#if defined(__gfx950__)
    __shared__ __align__(16) unsigned short Xs[64 * XSP];    // bf16 x tile [c][t*32+v]
    __shared__ __align__(16) unsigned short AsL[96 * ASP];   // bf16 Aeff^T [kw][v]
    __shared__ __align__(16) unsigned short XA[2 * 32 * KCP];// bf16 [t][w][kc=k*64+c]
    __shared__ float colsumL[96];
    __shared__ float sL[64], b2L[64], bcL[192];

    const int tid  = threadIdx.x;
    const int n    = blockIdx.x >> 7;          // 64 n
    const int t0   = (blockIdx.x & 127) * 2;   // 128 t-tiles of 2
    const int wave = tid >> 6, lane = tid & 63;
    const int l15  = lane & 15, quad = lane >> 4;

    const float* xblk = x + (size_t)n * 409600 + t0 * 25;

    // ================= phase 0: cooperative staging =================
    // Xs: per i, each wave loads one c-row's 50 contiguous floats (both t's)
#pragma unroll
    for (int i = 0; i < 8; ++i) {
        int idx = tid + i * 512;
        int c = idx >> 6, rem = idx & 63;
        int t = rem >> 5, v = rem & 31;
        float val = 0.f;
        if (v < 25) val = xblk[c * 6400 + t * 25 + v];
        Xs[c * XSP + t * 32 + v] = f2bf(val);
    }
    // AsL[kw][v] = Aeff[k][v][w], kw = k*32+w, zero-padded
#pragma unroll
    for (int i = 0; i < 6; ++i) {
        int idx = tid + i * 512;
        int kw = idx >> 5, v = idx & 31;
        int ks = kw >> 5, w = kw & 31;
        float a = 0.f;
        if (w < 25 && v < 25) {
            int ai = (ks * 25 + v) * 25 + w;
            a = A[ai] * PA[ai];
        }
        AsL[kw * ASP + v] = f2bf(a);
    }
    if (tid < 64) {
        float sc = gamma_[tid] * rsqrtf(var_[tid] + 1e-5f);
        sL[tid]  = sc;
        b2L[tid] = beta_[tid] - mean_[tid] * sc;
    }
    if (tid < 192) bcL[tid] = bc[tid];

    // W2 fragments (phase 2) prefetched from global Wc (16 KB, L2-hot):
    // W2[co][k*64+c] = Wc[k*64+co][c]
    const int tB = wave & 1, cot = wave >> 1;   // also reused as (tA, q) in phase 1
    union U8 { short8 v; unsigned short s[8]; };
    short8 wf[6];
#pragma unroll
    for (int ks = 0; ks < 6; ++ks) {
        int k = ks >> 1;
        int co = cot * 16 + l15;
        int cpart = (ks & 1) * 32 + quad * 8;
        const float* wp = &Wc[(k * 64 + co) * 64 + cpart];
        U8 u;
#pragma unroll
        for (int j = 0; j < 8; ++j) u.s[j] = f2bf(wp[j]);
        wf[ks] = u.v;
    }

    __syncthreads();   // barrier 1: Xs + AsL ready

    // ================= phase 1: A'  XA^T(kw,c) = Aeff^T(kw,v) @ X_t(v,c) =================
    // wave -> tA = wave&1, q = wave>>1; nt in {q&1, (q&1)+2}; mt in {q>>1 + 2m}
    const int tA  = tB;
    const int nt0 = cot & 1;
    const int mt0 = cot >> 1;

    short8 aA[3], xb[2];
#pragma unroll
    for (int m = 0; m < 3; ++m)
        aA[m] = *(const short8*)&AsL[((mt0 + 2 * m) * 16 + l15) * ASP + quad * 8];
#pragma unroll
    for (int h = 0; h < 2; ++h)
        xb[h] = *(const short8*)&Xs[((nt0 + 2 * h) * 16 + l15) * XSP + tA * 32 + quad * 8];

    unsigned short* xaw = &XA[tA * 32 * KCP];
#pragma unroll
    for (int h = 0; h < 2; ++h) {
        int ntc = (nt0 + 2 * h) * 16 + l15;
#pragma unroll
        for (int m = 0; m < 3; ++m) {
            floatx4 z0 = {0.f, 0.f, 0.f, 0.f};
            floatx4 d = __builtin_amdgcn_mfma_f32_16x16x32_bf16(aA[m], xb[h], z0, 0, 0, 0);
            int mt = mt0 + 2 * m;
#pragma unroll
            for (int r = 0; r < 4; ++r) {
                int kw = mt * 16 + quad * 4 + r;
                int ww = kw & 31, ks = kw >> 5;
                xaw[ww * KCP + ks * 64 + ntc] = f2bf(d[r]);
            }
        }
    }

    // colsum[k*32+w] = sum_v Aeff (for conv-bias folding), from AsL
    if (tid < 96) {
        float s = 0.f;
        for (int v = 0; v < 25; ++v) s += bf2f(AsL[tid * ASP + v]);
        colsumL[tid] = s;
    }

    __syncthreads();   // barrier 2: XA + colsum ready

    // ================= phase 2: B'  Z(co,w) = W2(co,kc) @ XA(kc,w) + epilogue =================
    float* oblk = out + (size_t)n * 409600 + t0 * 25;
#pragma unroll
    for (int wt = 0; wt < 2; ++wt) {
        const unsigned short* xr = &XA[tB * 32 * KCP + (wt * 16 + l15) * KCP];
        floatx4 zacc = {0.f, 0.f, 0.f, 0.f};
#pragma unroll
        for (int ks = 0; ks < 6; ++ks) {
            short8 bfr = *(const short8*)&xr[ks * 32 + quad * 8];
            zacc = __builtin_amdgcn_mfma_f32_16x16x32_bf16(wf[ks], bfr, zacc, 0, 0, 0);
        }
        int w = wt * 16 + l15;
        if (w < 25) {
            float cs0 = colsumL[w], cs1 = colsumL[32 + w], cs2 = colsumL[64 + w];
#pragma unroll
            for (int r = 0; r < 4; ++r) {
                int co = cot * 16 + quad * 4 + r;
                float bterm = bcL[co] * cs0 + bcL[64 + co] * cs1 + bcL[128 + co] * cs2;
                float xres = bf2f(Xs[co * XSP + tB * 32 + w]);
                float val = sL[co] * (zacc[r] + bterm) + b2L[co] + xres;
                oblk[co * 6400 + tB * 25 + w] = fmaxf(val, 0.f);
            }
        }
    }
#else
    (void)x; (void)A; (void)PA; (void)Wc; (void)bc;
    (void)gamma_; (void)beta_; (void)mean_; (void)var_; (void)out;
#endif
}

extern "C" void kernel_launch(void* const* d_in, const int* in_sizes, int n_in,
                              void* d_out, int out_size, void* d_ws, size_t ws_size,
                              hipStream_t stream) {
    (void)in_sizes; (void)n_in; (void)d_ws; (void)ws_size; (void)out_size;
    gcn_fused<<<dim3(64 * 128), dim3(512), 0, stream>>>(
        (const float*)d_in[0],   // x
        (const float*)d_in[1],   // A
        (const float*)d_in[2],   // PA
        (const float*)d_in[3],   // Wc
        (const float*)d_in[4],   // bc
        (const float*)d_in[5],   // gamma
        (const float*)d_in[6],   // beta
        (const float*)d_in[7],   // mean
        (const float*)d_in[8],   // var
        (float*)d_out);
}

// Round 7
// 317.341 us; speedup vs baseline: 1.2976x; 1.1872x over previous
//
#include <hip/hip_runtime.h>

typedef __attribute__((ext_vector_type(8))) short short8;
typedef __attribute__((ext_vector_type(4))) float floatx4;
typedef float float4u __attribute__((ext_vector_type(4), aligned(4)));

#define KCP 200    // XA row pitch (shorts): 400B rows

__device__ __forceinline__ float bf2f(unsigned short u) {
    unsigned int xx = ((unsigned int)u) << 16;
    return __uint_as_float(xx);
}
__device__ __forceinline__ unsigned short f2bf(float f) {
    unsigned int xx = __float_as_uint(f);
    unsigned int r = (xx + 0x7fffu + ((xx >> 16) & 1u)) >> 16;
    return (unsigned short)r;
}

// d_ws layout (bytes):
//   [0     ..  6144) Aefft bf16 [kw=96][quad=4][8]   A'-fragment table
//   [6144  .. 30720) W2p   bf16 [ks=6][co=64][quad=4][8]  B'-W2 fragment table
//   [30720 .. 37120) bt2   f32  [co=64][w=25]  folded bias+BN table
//   [37120 .. 37376) sLg   f32  [64]

// ---------------- prep: block-invariant tables, runs once per launch ----------------
__global__ void gcn_prep(const float* __restrict__ A,  const float* __restrict__ PA,
                         const float* __restrict__ Wc, const float* __restrict__ bc,
                         const float* __restrict__ g,  const float* __restrict__ b,
                         const float* __restrict__ mu, const float* __restrict__ var_,
                         unsigned short* __restrict__ Aefft, unsigned short* __restrict__ W2p,
                         float* __restrict__ bt2, float* __restrict__ sLg)
{
    int gtid = blockIdx.x * 256 + threadIdx.x;   // 8*256 = 2048 threads
    // Aefft[((kw*4+quad)*8+j)] = Aeff[k][v=quad*8+j][w=kw&31], zero-padded
    for (int idx = gtid; idx < 3072; idx += 2048) {
        int j = idx & 7, quad = (idx >> 3) & 3, kw = idx >> 5;
        int v = quad * 8 + j, k = kw >> 5, w = kw & 31;
        float a = 0.f;
        if (v < 25 && w < 25) { int ai = (k * 25 + v) * 25 + w; a = A[ai] * PA[ai]; }
        Aefft[idx] = f2bf(a);
    }
    // W2p[((ks*256 + co*4 + quad)*8 + j)] = Wc[(ks>>1)*64+co][(ks&1)*32+quad*8+j]
    for (int idx = gtid; idx < 12288; idx += 2048) {
        int j = idx & 7, quad = (idx >> 3) & 3, co = (idx >> 5) & 63, ks = idx >> 11;
        int k = ks >> 1, c = (ks & 1) * 32 + quad * 8 + j;
        W2p[idx] = f2bf(Wc[(k * 64 + co) * 64 + c]);
    }
    if (gtid < 64) sLg[gtid] = g[gtid] * rsqrtf(var_[gtid] + 1e-5f);
    // bt2[co*25+w] = s*sum_k bc[k*64+co]*colsum_k[w] + (b - mu*s)
    for (int idx = gtid; idx < 1600; idx += 2048) {
        int co = idx / 25, w = idx - co * 25;
        float s = g[co] * rsqrtf(var_[co] + 1e-5f);
        float acc = 0.f;
        for (int k = 0; k < 3; ++k) {
            float csum = 0.f;
            for (int v = 0; v < 25; ++v) { int ai = (k * 25 + v) * 25 + w; csum += A[ai] * PA[ai]; }
            acc += bc[k * 64 + co] * csum;
        }
        bt2[idx] = s * acc + (b[co] - mu[co] * s);
    }
}

// ---------------- main: LDS = XA 25600 + bt 6400 + sS 256 = 32256 B ----------------
__global__ __launch_bounds__(512) void gcn_main(
    const float* __restrict__ x, const unsigned short* __restrict__ Aefft,
    const unsigned short* __restrict__ W2p, const float* __restrict__ bt2,
    const float* __restrict__ sLg, float* __restrict__ out)
{
#if defined(__gfx950__)
    __shared__ __align__(16) unsigned short XA[2 * 32 * KCP];  // bf16 [t][w][kc]
    __shared__ __align__(16) float btS[1600];
    __shared__ float sS[64];

    const int tid  = threadIdx.x;
    const int n    = blockIdx.x >> 7;
    const int t0   = (blockIdx.x & 127) * 2;
    const int wave = tid >> 6, lane = tid & 63;
    const int l15  = lane & 15, quad = lane >> 4;

    const float* xblk = x + (size_t)n * 409600 + t0 * 25;

    // stage epilogue tables (coalesced; consumed after the barrier)
    if (tid < 400) ((float4*)btS)[tid] = ((const float4*)bt2)[tid];
    if (tid >= 448) sS[tid - 448] = sLg[tid - 448];

    const int tA  = wave & 1, q = wave >> 1;
    const int nt0 = q & 1,  mt0 = q >> 1;
    const int cot = q;                 // phase-2 roles: tB = tA, cot = q

    union U8 { short8 v; unsigned short s[8]; };

    // A' fragments: 3 contiguous-1KB wave reads from the table
    short8 aA[3];
#pragma unroll
    for (int m = 0; m < 3; ++m)
        aA[m] = *(const short8*)&Aefft[(((mt0 + 2 * m) * 16 + l15) * 4 + quad) * 8];

    // W2 fragments for phase 2 (issue early; contiguous-1KB wave reads)
    short8 wf[6];
#pragma unroll
    for (int ks = 0; ks < 6; ++ks)
        wf[ks] = *(const short8*)&W2p[((ks * 256 + (cot * 16 + l15) * 4 + quad) * 8)];

    // x B-fragments straight from global: lane (l15,quad) -> c = nt*16+l15, v = quad*8..+7
    short8 xb[2];
#pragma unroll
    for (int h = 0; h < 2; ++h) {
        int c = (nt0 + 2 * h) * 16 + l15;
        const float* base = xblk + c * 6400 + tA * 25;
        U8 u;
        if (quad < 3) {
            float4u f0 = *(const float4u*)(base + quad * 8);
            float4u f1 = *(const float4u*)(base + quad * 8 + 4);
#pragma unroll
            for (int j = 0; j < 4; ++j) { u.s[j] = f2bf(f0[j]); u.s[4 + j] = f2bf(f1[j]); }
        } else {
            float xv = base[24];
            u.s[0] = f2bf(xv);
#pragma unroll
            for (int j = 1; j < 8; ++j) u.s[j] = 0;
        }
        xb[h] = u.v;
    }

    // ---- phase 1: A'  D[kw][c] = Aefft[kw][v] * X_t[v][c]; scatter to XA[t][w][kc] ----
    unsigned short* xaw = &XA[tA * 32 * KCP];
#pragma unroll
    for (int h = 0; h < 2; ++h) {
        int ntc = (nt0 + 2 * h) * 16 + l15;
#pragma unroll
        for (int m = 0; m < 3; ++m) {
            floatx4 z0 = {0.f, 0.f, 0.f, 0.f};
            floatx4 d = __builtin_amdgcn_mfma_f32_16x16x32_bf16(aA[m], xb[h], z0, 0, 0, 0);
            int mt = mt0 + 2 * m;
#pragma unroll
            for (int r = 0; r < 4; ++r) {
                int kw = mt * 16 + quad * 4 + r;
                int ww = kw & 31, ks = kw >> 5;
                xaw[ww * KCP + ks * 64 + ntc] = f2bf(d[r]);
            }
        }
    }

    __syncthreads();   // the only barrier

    // ---- phase 2: B'  Z[co][w] = W2[co][kc] * XA[kc][w] + epilogue ----
    const int tB = tA;
    float* oblk = out + (size_t)n * 409600 + t0 * 25;
#pragma unroll
    for (int wt = 0; wt < 2; ++wt) {
        const unsigned short* xr = &XA[tB * 32 * KCP + (wt * 16 + l15) * KCP];
        floatx4 zacc = {0.f, 0.f, 0.f, 0.f};
#pragma unroll
        for (int ks = 0; ks < 6; ++ks) {
            short8 bfr = *(const short8*)&xr[ks * 32 + quad * 8];
            zacc = __builtin_amdgcn_mfma_f32_16x16x32_bf16(wf[ks], bfr, zacc, 0, 0, 0);
        }
        int w = wt * 16 + l15;
        if (w < 25) {
#pragma unroll
            for (int r = 0; r < 4; ++r) {
                int co = cot * 16 + quad * 4 + r;
                float xres = xblk[co * 6400 + tB * 25 + w];
                float val = sS[co] * zacc[r] + btS[co * 25 + w] + xres;
                oblk[co * 6400 + tB * 25 + w] = fmaxf(val, 0.f);
            }
        }
    }
#else
    (void)x; (void)Aefft; (void)W2p; (void)bt2; (void)sLg; (void)out;
#endif
}

extern "C" void kernel_launch(void* const* d_in, const int* in_sizes, int n_in,
                              void* d_out, int out_size, void* d_ws, size_t ws_size,
                              hipStream_t stream) {
    (void)in_sizes; (void)n_in; (void)ws_size; (void)out_size;
    unsigned short* Aefft = (unsigned short*)d_ws;
    unsigned short* W2p   = (unsigned short*)((char*)d_ws + 6144);
    float* bt2            = (float*)((char*)d_ws + 30720);
    float* sLg            = (float*)((char*)d_ws + 37120);

    gcn_prep<<<dim3(8), dim3(256), 0, stream>>>(
        (const float*)d_in[1], (const float*)d_in[2], (const float*)d_in[3],
        (const float*)d_in[4], (const float*)d_in[5], (const float*)d_in[6],
        (const float*)d_in[7], (const float*)d_in[8],
        Aefft, W2p, bt2, sLg);

    gcn_main<<<dim3(64 * 128), dim3(512), 0, stream>>>(
        (const float*)d_in[0], Aefft, W2p, bt2, sLg, (float*)d_out);
}